// Round 1
// baseline (2412.098 us; speedup 1.0000x reference)
//
#include <hip/hip_runtime.h>
#include <hip/hip_bf16.h>

// MHA: B=2, S=2048, D=1024, H=16, hd=64, fp32 in/out.
// Round 1: correct fp32 baseline.
//   gemm_xwT<1>: Y = X@W^T + b  written head-major [B,H,S,64]   (Q,K,V proj)
//   attn_kernel: flash-style online-softmax attention, 16 q-rows/block,
//                4 waves x 512 keys, merge partials in LDS
//   gemm_xwT<0>: Y = O@Wo^T + bo row-major [B*S, D] -> d_out
// Workspace: qbuf/kbuf/vbuf/obuf = 4 x 16 MB = 64 MB (assumed <= ws_size).

constexpr int D_MODEL = 1024;
constexpr int S_LEN   = 2048;
constexpr int BATCH   = 2;
constexpr int NH      = 16;
constexpr int HD      = 64;
constexpr int ROWS    = BATCH * S_LEN;  // 4096

// ---------------- GEMM: Y = X @ W^T + b ----------------
// X: [ROWS, D] row-major, W: [D, D] row-major (torch Linear convention).
// MODE 0: Y row-major [ROWS, D].  MODE 1: Y head-major [B, H, S, HD].
template <int MODE>
__global__ __launch_bounds__(256) void gemm_xwT(const float* __restrict__ X,
                                                const float* __restrict__ W,
                                                const float* __restrict__ bias,
                                                float* __restrict__ Y) {
  __shared__ float Xs[16][64];  // [k][m]
  __shared__ float Ws[16][64];  // [k][n]
  const int tid  = threadIdx.x;
  const int row0 = blockIdx.x * 64;
  const int col0 = blockIdx.y * 64;
  // load mapping: each thread one float4 of X and one of W per k-tile
  const int lk = (tid & 3) * 4;  // k offset 0,4,8,12
  const int lr = tid >> 2;       // row/col within tile 0..63
  const float* Xp = X + (size_t)(row0 + lr) * D_MODEL + lk;
  const float* Wp = W + (size_t)(col0 + lr) * D_MODEL + lk;
  const int tx = tid & 15, ty = tid >> 4;

  float acc[4][4];
#pragma unroll
  for (int i = 0; i < 4; i++)
#pragma unroll
    for (int j = 0; j < 4; j++) acc[i][j] = 0.f;

  for (int k0 = 0; k0 < D_MODEL; k0 += 16) {
    float4 xv = *(const float4*)(Xp + k0);
    float4 wv = *(const float4*)(Wp + k0);
    __syncthreads();  // previous iter's reads done before overwrite
    Xs[lk + 0][lr] = xv.x; Xs[lk + 1][lr] = xv.y;
    Xs[lk + 2][lr] = xv.z; Xs[lk + 3][lr] = xv.w;
    Ws[lk + 0][lr] = wv.x; Ws[lk + 1][lr] = wv.y;
    Ws[lk + 2][lr] = wv.z; Ws[lk + 3][lr] = wv.w;
    __syncthreads();
#pragma unroll
    for (int k = 0; k < 16; k++) {
      float4 av = *(const float4*)&Xs[k][ty * 4];
      float4 bv = *(const float4*)&Ws[k][tx * 4];
      float a[4] = {av.x, av.y, av.z, av.w};
      float b[4] = {bv.x, bv.y, bv.z, bv.w};
#pragma unroll
      for (int i = 0; i < 4; i++)
#pragma unroll
        for (int j = 0; j < 4; j++) acc[i][j] += a[i] * b[j];
    }
  }

#pragma unroll
  for (int i = 0; i < 4; i++) {
    const int r  = row0 + ty * 4 + i;
    const int bb = r >> 11;      // r / S_LEN
    const int s  = r & 2047;     // r % S_LEN
#pragma unroll
    for (int j = 0; j < 4; j++) {
      const int c = col0 + tx * 4 + j;
      const float v = acc[i][j] + bias[c];
      if (MODE == 0) {
        Y[(size_t)r * D_MODEL + c] = v;
      } else {
        const int h = c >> 6, d = c & 63;
        Y[((size_t)(bb * NH + h) * S_LEN + s) * HD + d] = v;
      }
    }
  }
}

// ---------------- Attention ----------------
// grid: (S/16, H, B), 256 threads = 4 waves.
// Block handles 16 q rows; wave w handles keys [w*512, (w+1)*512) with
// per-wave online softmax; partials merged through LDS at the end.
__global__ __launch_bounds__(256) void attn_kernel(const float* __restrict__ Qh,
                                                   const float* __restrict__ Kh,
                                                   const float* __restrict__ Vh,
                                                   float* __restrict__ O) {
  const int qt   = blockIdx.x;   // 0..127
  const int h    = blockIdx.y;   // 0..15
  const int bb   = blockIdx.z;   // 0..1
  const int tid  = threadIdx.x;
  const int w    = tid >> 6;     // wave 0..3
  const int lane = tid & 63;
  const int q    = lane & 15;    // q row within tile
  const int jg   = lane >> 4;    // 0..3: j subgroup, also owns d-range jg*16..+15

  __shared__ float obuf[4][16][64];
  __shared__ float mbuf[4][16];
  __shared__ float lbuf[4][16];

  const size_t bh = (size_t)(bb * NH + h);
  const float4* Q4 = (const float4*)(Qh + bh * S_LEN * HD);
  const float4* K4 = (const float4*)(Kh + bh * S_LEN * HD);
  const float4* V4 = (const float4*)(Vh + bh * S_LEN * HD);

  // Q row in registers, pre-scaled by 1/sqrt(hd)
  float qr[64];
  {
    const int qrow = qt * 16 + q;
#pragma unroll
    for (int c = 0; c < 16; c++) {
      float4 v = Q4[qrow * 16 + c];
      qr[c * 4 + 0] = v.x * 0.125f;
      qr[c * 4 + 1] = v.y * 0.125f;
      qr[c * 4 + 2] = v.z * 0.125f;
      qr[c * 4 + 3] = v.w * 0.125f;
    }
  }

  float m = -1e30f, l = 0.f;
  float oacc[16];
#pragma unroll
  for (int i = 0; i < 16; i++) oacc[i] = 0.f;

  const int j0 = w * 512;
  for (int jb = j0; jb < j0 + 512; jb += 4) {
    const int j = jb + jg;
    // score = (q . k) * scale   (scale folded into qr)
    float s = 0.f;
#pragma unroll
    for (int c = 0; c < 16; c++) {
      float4 kv = K4[j * 16 + c];
      s += qr[c * 4 + 0] * kv.x + qr[c * 4 + 1] * kv.y +
           qr[c * 4 + 2] * kv.z + qr[c * 4 + 3] * kv.w;
    }
    // max over the 4 jg lanes sharing this q
    float smax = s;
    smax = fmaxf(smax, __shfl_xor(smax, 16));
    smax = fmaxf(smax, __shfl_xor(smax, 32));
    const float mnew   = fmaxf(m, smax);
    const float factor = __expf(m - mnew);
    const float p      = __expf(s - mnew);
    l = l * factor + p;
#pragma unroll
    for (int i = 0; i < 16; i++) oacc[i] *= factor;
    m = mnew;
    // gather the 4 p values of this q (lanes q, q+16, q+32, q+48)
    const float pk0 = p;
    const float pk1 = __shfl_xor(p, 16);  // from lane jg^1
    const float pk2 = __shfl_xor(p, 32);  // jg^2
    const float pk3 = __shfl_xor(p, 48);  // jg^3
    const float pk[4] = {pk0, pk1, pk2, pk3};
#pragma unroll
    for (int kk = 0; kk < 4; kk++) {
      const int jj = jb + (jg ^ kk);  // pk[kk] is p(q, jb + (jg^kk))
#pragma unroll
      for (int c = 0; c < 4; c++) {
        float4 vv = V4[jj * 16 + jg * 4 + c];
        oacc[c * 4 + 0] += pk[kk] * vv.x;
        oacc[c * 4 + 1] += pk[kk] * vv.y;
        oacc[c * 4 + 2] += pk[kk] * vv.z;
        oacc[c * 4 + 3] += pk[kk] * vv.w;
      }
    }
  }

  // combine per-lane partial l across the 4 jg lanes (m already common)
  l += __shfl_xor(l, 16);
  l += __shfl_xor(l, 32);

  if (jg == 0) {
    mbuf[w][q] = m;
    lbuf[w][q] = l;
  }
#pragma unroll
  for (int c = 0; c < 4; c++) {
    float4 ov = make_float4(oacc[c * 4 + 0], oacc[c * 4 + 1],
                            oacc[c * 4 + 2], oacc[c * 4 + 3]);
    *(float4*)&obuf[w][q][jg * 16 + c * 4] = ov;
  }
  __syncthreads();

  // merge 4 wave-partials; write merged-heads row-major [B, S, D]
#pragma unroll
  for (int i = 0; i < 4; i++) {
    const int e  = tid + i * 256;
    const int qq = e >> 6, d = e & 63;
    const float m0 = mbuf[0][qq], m1 = mbuf[1][qq], m2 = mbuf[2][qq], m3 = mbuf[3][qq];
    const float M  = fmaxf(fmaxf(m0, m1), fmaxf(m2, m3));
    const float f0 = __expf(m0 - M), f1 = __expf(m1 - M);
    const float f2 = __expf(m2 - M), f3 = __expf(m3 - M);
    const float L = f0 * lbuf[0][qq] + f1 * lbuf[1][qq] +
                    f2 * lbuf[2][qq] + f3 * lbuf[3][qq];
    const float val = (f0 * obuf[0][qq][d] + f1 * obuf[1][qq][d] +
                       f2 * obuf[2][qq][d] + f3 * obuf[3][qq][d]) / L;
    O[((size_t)bb * S_LEN + qt * 16 + qq) * D_MODEL + h * HD + d] = val;
  }
}

extern "C" void kernel_launch(void* const* d_in, const int* in_sizes, int n_in,
                              void* d_out, int out_size, void* d_ws, size_t ws_size,
                              hipStream_t stream) {
  const float* query = (const float*)d_in[0];
  const float* key   = (const float*)d_in[1];
  const float* value = (const float*)d_in[2];
  const float* Wq = (const float*)d_in[3];
  const float* bq = (const float*)d_in[4];
  const float* Wk = (const float*)d_in[5];
  const float* bk = (const float*)d_in[6];
  const float* Wv = (const float*)d_in[7];
  const float* bv = (const float*)d_in[8];
  const float* Wo = (const float*)d_in[9];
  const float* bo = (const float*)d_in[10];
  float* out = (float*)d_out;

  float* ws   = (float*)d_ws;
  const size_t TSZ = (size_t)ROWS * D_MODEL;  // 4,194,304
  float* qbuf = ws;            // head-major [B,H,S,HD]
  float* kbuf = ws + TSZ;      // head-major
  float* vbuf = ws + 2 * TSZ;  // head-major
  float* obuf = ws + 3 * TSZ;  // row-major [B*S, D]

  dim3 gg(ROWS / 64, D_MODEL / 64);  // (64, 16)
  hipLaunchKernelGGL((gemm_xwT<1>), gg, dim3(256), 0, stream, query, Wq, bq, qbuf);
  hipLaunchKernelGGL((gemm_xwT<1>), gg, dim3(256), 0, stream, key,   Wk, bk, kbuf);
  hipLaunchKernelGGL((gemm_xwT<1>), gg, dim3(256), 0, stream, value, Wv, bv, vbuf);

  dim3 ga(S_LEN / 16, NH, BATCH);  // (128, 16, 2)
  hipLaunchKernelGGL(attn_kernel, ga, dim3(256), 0, stream, qbuf, kbuf, vbuf, obuf);

  hipLaunchKernelGGL((gemm_xwT<0>), gg, dim3(256), 0, stream, obuf, Wo, bo, out);
}

// Round 2
// 683.733 us; speedup vs baseline: 3.5278x; 3.5278x over previous
//
#include <hip/hip_runtime.h>
#include <hip/hip_bf16.h>

// MHA: B=2, S=2048, D=1024, H=16, hd=64, fp32 in/out.
// Round 2: MFMA bf16 flash attention.
//   gemm_xwT<1>: Y = (X@W^T + b)*scale -> bf16 head-major [B,H,S,64]  (Q,K)
//   gemm_xwT<2>: Y = X@W^T + b -> bf16 TRANSPOSED head-major [B,H,64,S] (V^T)
//   attn_kernel: flash (no-max online softmax: scores bounded), MFMA 16x16x32
//   gemm_xwT<0>: Y = O@Wo^T + bo fp32 row-major -> d_out

constexpr int D_MODEL = 1024;
constexpr int S_LEN   = 2048;
constexpr int BATCH   = 2;
constexpr int NH      = 16;
constexpr int HD      = 64;
constexpr int ROWS    = BATCH * S_LEN;  // 4096

typedef __attribute__((ext_vector_type(8))) short short8;
typedef __attribute__((ext_vector_type(4))) float float4a;

static __device__ __forceinline__ unsigned short f2bf(float f) {
  union { float f; unsigned u; } v{f};
  unsigned r = v.u + 0x7FFFu + ((v.u >> 16) & 1u);  // RNE
  return (unsigned short)(r >> 16);
}

// ---------------- GEMM: Y = X @ W^T + b ----------------
// MODE 0: fp32 row-major [ROWS, D].
// MODE 1: bf16 head-major [B,H,S,HD], result *= scale.
// MODE 2: bf16 transposed head-major [B,H,HD,S] (LDS-transposed epilogue).
template <int MODE>
__global__ __launch_bounds__(256) void gemm_xwT(const float* __restrict__ X,
                                                const float* __restrict__ W,
                                                const float* __restrict__ bias,
                                                void* __restrict__ Yv,
                                                float scale) {
  __shared__ float Xs[16][64];  // [k][m]
  __shared__ float Ws[16][64];  // [k][n]
  const int tid  = threadIdx.x;
  const int row0 = blockIdx.x * 64;
  const int col0 = blockIdx.y * 64;
  const int lk = (tid & 3) * 4;
  const int lr = tid >> 2;
  const float* Xp = X + (size_t)(row0 + lr) * D_MODEL + lk;
  const float* Wp = W + (size_t)(col0 + lr) * D_MODEL + lk;
  const int tx = tid & 15, ty = tid >> 4;

  float acc[4][4];
#pragma unroll
  for (int i = 0; i < 4; i++)
#pragma unroll
    for (int j = 0; j < 4; j++) acc[i][j] = 0.f;

  for (int k0 = 0; k0 < D_MODEL; k0 += 16) {
    float4 xv = *(const float4*)(Xp + k0);
    float4 wv = *(const float4*)(Wp + k0);
    __syncthreads();
    Xs[lk + 0][lr] = xv.x; Xs[lk + 1][lr] = xv.y;
    Xs[lk + 2][lr] = xv.z; Xs[lk + 3][lr] = xv.w;
    Ws[lk + 0][lr] = wv.x; Ws[lk + 1][lr] = wv.y;
    Ws[lk + 2][lr] = wv.z; Ws[lk + 3][lr] = wv.w;
    __syncthreads();
#pragma unroll
    for (int k = 0; k < 16; k++) {
      float4 av = *(const float4*)&Xs[k][ty * 4];
      float4 bv = *(const float4*)&Ws[k][tx * 4];
      float a[4] = {av.x, av.y, av.z, av.w};
      float b[4] = {bv.x, bv.y, bv.z, bv.w};
#pragma unroll
      for (int i = 0; i < 4; i++)
#pragma unroll
        for (int j = 0; j < 4; j++) acc[i][j] += a[i] * b[j];
    }
  }

  const int h = col0 >> 6;  // head (tile width 64 == HD)

  if (MODE == 0) {
    float* Y = (float*)Yv;
#pragma unroll
    for (int i = 0; i < 4; i++) {
      const int r = row0 + ty * 4 + i;
#pragma unroll
      for (int j = 0; j < 4; j++) {
        const int c = col0 + tx * 4 + j;
        Y[(size_t)r * D_MODEL + c] = acc[i][j] + bias[c];
      }
    }
  } else if (MODE == 1) {
    unsigned short* Y = (unsigned short*)Yv;
#pragma unroll
    for (int i = 0; i < 4; i++) {
      const int r  = row0 + ty * 4 + i;
      const int bb = r >> 11, s = r & 2047;
      ushort4 pk;
      unsigned short* pp = (unsigned short*)&pk;
#pragma unroll
      for (int j = 0; j < 4; j++) {
        const int c = col0 + tx * 4 + j;
        pp[j] = f2bf((acc[i][j] + bias[c]) * scale);
      }
      *(ushort4*)&Y[(((size_t)(bb * NH + h)) * S_LEN + s) * HD + tx * 4] = pk;
    }
  } else {  // MODE == 2: V^T
    __shared__ unsigned short Ts[64][74];  // [s_local][d_local], stride 74 (bank-tuned)
#pragma unroll
    for (int i = 0; i < 4; i++) {
      const int sl = ty * 4 + i;
#pragma unroll
      for (int j = 0; j < 4; j++) {
        const int c = col0 + tx * 4 + j;
        Ts[sl][tx * 4 + j] = f2bf(acc[i][j] + bias[c]);
      }
    }
    __syncthreads();
    unsigned short* Y = (unsigned short*)Yv;
    const int bb = row0 >> 11, s0 = row0 & 2047;
#pragma unroll
    for (int rr = 0; rr < 2; rr++) {
      const int idx = tid + rr * 256;        // 512 chunks of 8 bf16
      const int d = idx >> 3, sc = (idx & 7) * 8;
      unsigned short tmp[8];
#pragma unroll
      for (int e = 0; e < 8; e++) tmp[e] = Ts[sc + e][d];
      short8 v = *(short8*)tmp;
      *(short8*)&Y[(((size_t)(bb * NH + h)) * HD + d) * S_LEN + s0 + sc] = v;
    }
  }
}

// ---------------- Flash attention (MFMA bf16) ----------------
// grid: (S/128, H, B), 256 threads = 4 waves. Wave w owns q rows
// [w*32, w*32+32). Loop over 64-key tiles; K tile + V^T tile staged in LDS.
// S^T = K·Q^T (M=key, N=q) so per-q softmax reduction is in-lane + shfl.
// No running max: |s| <= ||q||*||k||/8 < ~16, exp() safe in fp32.
__global__ __launch_bounds__(256) void attn_kernel(
    const unsigned short* __restrict__ Qh, const unsigned short* __restrict__ Kh,
    const unsigned short* __restrict__ Vt, float* __restrict__ O) {
  const int qb = blockIdx.x;   // 0..15
  const int h  = blockIdx.y;
  const int bb = blockIdx.z;
  const int tid = threadIdx.x;
  const int w = tid >> 6, lane = tid & 63;
  const int l15 = lane & 15, quad = lane >> 4;

  __shared__ unsigned short Ks[64][72];      // [key][hd]   stride 144B
  __shared__ unsigned short Vs[64][72];      // [hd][key]   (V^T tile)
  __shared__ unsigned short Ps[4][32][72];   // per-wave P [q_local][key]

  const size_t bh = (size_t)(bb * NH + h);
  const unsigned short* Qp = Qh + bh * S_LEN * HD;
  const unsigned short* Kp = Kh + bh * S_LEN * HD;
  const unsigned short* Vp = Vt + bh * (size_t)HD * S_LEN;

  // Q fragments (B-operand): B[k=c*32+quad*8+j][n=q], q row = qb*128+w*32+qnt*16+l15
  short8 qf[2][2];
#pragma unroll
  for (int qnt = 0; qnt < 2; qnt++)
#pragma unroll
    for (int c = 0; c < 2; c++)
      qf[qnt][c] = *(const short8*)(Qp + (size_t)(qb * 128 + w * 32 + qnt * 16 + l15) * HD +
                                    c * 32 + quad * 8);

  float4a Oacc[2][4];
#pragma unroll
  for (int a = 0; a < 2; a++)
#pragma unroll
    for (int b = 0; b < 4; b++) Oacc[a][b] = (float4a){0.f, 0.f, 0.f, 0.f};
  float lp[2] = {0.f, 0.f};

  for (int kb = 0; kb < S_LEN; kb += 64) {
    __syncthreads();  // previous tile's LDS reads done
    {
      const unsigned short* src = Kp + (size_t)kb * HD;  // 8KB contiguous
#pragma unroll
      for (int r = 0; r < 2; r++) {
        const int idx = tid + r * 256;
        const int row = idx >> 3, cb = (idx & 7) * 8;
        *(short8*)&Ks[row][cb] = *(const short8*)(src + row * HD + cb);
      }
      const unsigned short* vsrc = Vp + kb;  // rows stride S_LEN
#pragma unroll
      for (int r = 0; r < 2; r++) {
        const int idx = tid + r * 256;
        const int row = idx >> 3, cb = (idx & 7) * 8;
        *(short8*)&Vs[row][cb] = *(const short8*)(vsrc + (size_t)row * S_LEN + cb);
      }
    }
    __syncthreads();

    // S^T = K·Q^T, then exp -> P (bf16) into per-wave LDS
#pragma unroll
    for (int mt = 0; mt < 4; mt++) {
      short8 a0 = *(const short8*)&Ks[mt * 16 + l15][quad * 8];
      short8 a1 = *(const short8*)&Ks[mt * 16 + l15][32 + quad * 8];
#pragma unroll
      for (int qnt = 0; qnt < 2; qnt++) {
        float4a s = (float4a){0.f, 0.f, 0.f, 0.f};
        s = __builtin_amdgcn_mfma_f32_16x16x32_bf16(a0, qf[qnt][0], s, 0, 0, 0);
        s = __builtin_amdgcn_mfma_f32_16x16x32_bf16(a1, qf[qnt][1], s, 0, 0, 0);
        const float p0 = __expf(s[0]), p1 = __expf(s[1]);
        const float p2 = __expf(s[2]), p3 = __expf(s[3]);
        lp[qnt] += (p0 + p1) + (p2 + p3);
        const unsigned u01 = (unsigned)f2bf(p0) | ((unsigned)f2bf(p1) << 16);
        const unsigned u23 = (unsigned)f2bf(p2) | ((unsigned)f2bf(p3) << 16);
        unsigned short* prow = &Ps[w][qnt * 16 + l15][mt * 16 + quad * 4];
        *(unsigned*)(prow)     = u01;
        *(unsigned*)(prow + 2) = u23;
      }
    }
    asm volatile("s_waitcnt lgkmcnt(0)" ::: "memory");  // P write->read, same wave

    // O += P·V : A=P[q][key], B=V^T rows (hd) with contiguous keys
#pragma unroll
    for (int c = 0; c < 2; c++) {
      short8 pa0 = *(const short8*)&Ps[w][l15][c * 32 + quad * 8];
      short8 pa1 = *(const short8*)&Ps[w][16 + l15][c * 32 + quad * 8];
#pragma unroll
      for (int nt = 0; nt < 4; nt++) {
        short8 vb = *(const short8*)&Vs[nt * 16 + l15][c * 32 + quad * 8];
        Oacc[0][nt] = __builtin_amdgcn_mfma_f32_16x16x32_bf16(pa0, vb, Oacc[0][nt], 0, 0, 0);
        Oacc[1][nt] = __builtin_amdgcn_mfma_f32_16x16x32_bf16(pa1, vb, Oacc[1][nt], 0, 0, 0);
      }
    }
  }

  // reduce l over the 4 quads (keys were split across quads)
#pragma unroll
  for (int qnt = 0; qnt < 2; qnt++) {
    lp[qnt] += __shfl_xor(lp[qnt], 16);
    lp[qnt] += __shfl_xor(lp[qnt], 32);
  }

  // write O / l : Oacc[qnt][nt][reg] is (q = qnt*16+quad*4+reg, hd = nt*16+l15)
#pragma unroll
  for (int qnt = 0; qnt < 2; qnt++) {
#pragma unroll
    for (int reg = 0; reg < 4; reg++) {
      const float lsum = __shfl(lp[qnt], quad * 4 + reg);  // lane q holds l(q)
      const float rinv = 1.0f / lsum;
      const int q = qb * 128 + w * 32 + qnt * 16 + quad * 4 + reg;
      float* orow = O + ((size_t)bb * S_LEN + q) * D_MODEL + h * HD;
#pragma unroll
      for (int nt = 0; nt < 4; nt++)
        orow[nt * 16 + l15] = Oacc[qnt][nt][reg] * rinv;
    }
  }
}

extern "C" void kernel_launch(void* const* d_in, const int* in_sizes, int n_in,
                              void* d_out, int out_size, void* d_ws, size_t ws_size,
                              hipStream_t stream) {
  const float* query = (const float*)d_in[0];
  const float* key   = (const float*)d_in[1];
  const float* value = (const float*)d_in[2];
  const float* Wq = (const float*)d_in[3];
  const float* bq = (const float*)d_in[4];
  const float* Wk = (const float*)d_in[5];
  const float* bk = (const float*)d_in[6];
  const float* Wv = (const float*)d_in[7];
  const float* bv = (const float*)d_in[8];
  const float* Wo = (const float*)d_in[9];
  const float* bo = (const float*)d_in[10];
  float* out = (float*)d_out;

  char* ws = (char*)d_ws;
  const size_t TSZ = (size_t)ROWS * D_MODEL;             // 4,194,304 elems
  unsigned short* qbuf = (unsigned short*)(ws);                  // 8 MB bf16
  unsigned short* kbuf = (unsigned short*)(ws + 2 * TSZ);        // 8 MB bf16
  unsigned short* vtbuf = (unsigned short*)(ws + 4 * TSZ);       // 8 MB bf16 (V^T)
  float* obuf = (float*)(ws + 6 * TSZ);                          // 16 MB fp32

  dim3 gg(ROWS / 64, D_MODEL / 64);  // (64, 16)
  hipLaunchKernelGGL((gemm_xwT<1>), gg, dim3(256), 0, stream, query, Wq, bq,
                     (void*)qbuf, 0.125f);  // fold 1/sqrt(hd) into Q
  hipLaunchKernelGGL((gemm_xwT<1>), gg, dim3(256), 0, stream, key, Wk, bk,
                     (void*)kbuf, 1.0f);
  hipLaunchKernelGGL((gemm_xwT<2>), gg, dim3(256), 0, stream, value, Wv, bv,
                     (void*)vtbuf, 1.0f);

  dim3 ga(S_LEN / 128, NH, BATCH);  // (16, 16, 2)
  hipLaunchKernelGGL(attn_kernel, ga, dim3(256), 0, stream, qbuf, kbuf, vtbuf, obuf);

  hipLaunchKernelGGL((gemm_xwT<0>), gg, dim3(256), 0, stream, obuf, Wo, bo,
                     (void*)out, 1.0f);
}

// Round 3
// 273.127 us; speedup vs baseline: 8.8314x; 2.5033x over previous
//
#include <hip/hip_runtime.h>
#include <hip/hip_bf16.h>

// MHA: B=2, S=2048, D=1024, H=16, hd=64, fp32 in/out.
// Round 3: all GEMMs -> MFMA bf16 (m97 structure: 128x128 tile, BK=32,
//          global_load_lds width 16). Pipeline:
//   convert_bf16 : fp32 -> bf16 copies of query/key/value + 4 weights
//   gemm_qk      : Q = (x@Wq^T+bq)*0.125, K = x@Wk^T+bk -> bf16 head-major
//   gemm_v       : V^T -> bf16 [B,H,64,S] via swizzled LDS-transpose epilogue
//   attn_kernel  : flash MFMA attention (round 2) -> bf16 row-major O
//   gemm_o       : out = O@Wo^T + bo -> fp32 d_out

constexpr int D_MODEL = 1024;
constexpr int S_LEN   = 2048;
constexpr int BATCH   = 2;
constexpr int NH      = 16;
constexpr int HD      = 64;
constexpr int ROWS    = BATCH * S_LEN;  // 4096

typedef __attribute__((ext_vector_type(8))) short short8;
typedef __attribute__((ext_vector_type(4))) float float4a;

static __device__ __forceinline__ unsigned short f2bf(float f) {
  union { float f; unsigned u; } v{f};
  unsigned r = v.u + 0x7FFFu + ((v.u >> 16) & 1u);  // RNE
  return (unsigned short)(r >> 16);
}

// async 16B global -> LDS (wave-uniform LDS base + lane*16)
static __device__ __forceinline__ void async16(const void* g, void* l) {
  __builtin_amdgcn_global_load_lds(
      (const __attribute__((address_space(1))) unsigned int*)g,
      (__attribute__((address_space(3))) unsigned int*)l, 16, 0, 0);
}

// ---------------- fp32 -> bf16 convert ----------------
struct ConvArgs { const float* s[7]; unsigned short* d[7]; int n[7]; };

__global__ __launch_bounds__(256) void convert_bf16(ConvArgs a) {
  const int which = blockIdx.y;
  const int i = (blockIdx.x * 256 + threadIdx.x) * 8;
  if (i >= a.n[which]) return;
  const float4* s = (const float4*)(a.s[which] + i);
  float4 x = s[0], y = s[1];
  unsigned short t[8] = {f2bf(x.x), f2bf(x.y), f2bf(x.z), f2bf(x.w),
                         f2bf(y.x), f2bf(y.y), f2bf(y.z), f2bf(y.w)};
  *(short8*)(a.d[which] + i) = *(short8*)t;
}

// ---------------- MFMA bf16 GEMM: Y = A @ W^T (+bias) ----------------
// A: [ROWS, 1024] bf16 row-major. W: [1024, 1024] bf16 row-major ([n][k]).
// 128x128 block tile, BK=32, 4 waves each 64x64.
// MODE 0: bf16 head-major [B,H,S,64], value = (acc + bias)*scale
// MODE 2: bf16 V^T [B,H,64,S]  (swizzled LDS transpose epilogue)
// MODE 3: fp32 row-major [ROWS, 1024], value = acc + bias
template <int MODE>
static __device__ __forceinline__ void gemm_body(const unsigned short* __restrict__ A,
                                                 const unsigned short* __restrict__ W,
                                                 const float* __restrict__ bias,
                                                 void* __restrict__ Yv, float scale) {
  __shared__ unsigned short As[128][32];
  __shared__ unsigned short Bs[128][32];
  const int tid = threadIdx.x;
  const int w = tid >> 6, lane = tid & 63;
  const int l15 = lane & 15, quad = lane >> 4;
  const int row0 = blockIdx.x * 128, col0 = blockIdx.y * 128;
  const int wm = (w & 1) * 64, wn = (w >> 1) * 64;

  // staging: chunk-linear idx (w*2+i)*64+lane -> row=idx>>2, chunk=idx&3
  const int srow = (w * 128 + lane) >> 2;  // issue 0 row; issue 1 = +16
  const int schk = lane & 3;
  const unsigned short* Ap = A + (size_t)(row0 + srow) * D_MODEL + schk * 8;
  const unsigned short* Wp = W + (size_t)(col0 + srow) * D_MODEL + schk * 8;
  char* lA0 = (char*)As + w * 2048;
  char* lA1 = lA0 + 1024;
  char* lB0 = (char*)Bs + w * 2048;
  char* lB1 = lB0 + 1024;

  float4a acc[4][4];
#pragma unroll
  for (int i = 0; i < 4; i++)
#pragma unroll
    for (int j = 0; j < 4; j++) acc[i][j] = (float4a){0.f, 0.f, 0.f, 0.f};

  for (int kt = 0; kt < D_MODEL; kt += 32) {
    __syncthreads();  // prior ds_reads done before LDS overwrite
    async16(Ap + kt, lA0);
    async16(Ap + kt + 16 * D_MODEL, lA1);
    async16(Wp + kt, lB0);
    async16(Wp + kt + 16 * D_MODEL, lB1);
    __syncthreads();  // drains vmcnt -> tiles resident

    short8 af[4], bf[4];
#pragma unroll
    for (int mt = 0; mt < 4; mt++)
      af[mt] = *(const short8*)&As[wm + mt * 16 + l15][quad * 8];
#pragma unroll
    for (int nt = 0; nt < 4; nt++)
      bf[nt] = *(const short8*)&Bs[wn + nt * 16 + l15][quad * 8];
#pragma unroll
    for (int mt = 0; mt < 4; mt++)
#pragma unroll
      for (int nt = 0; nt < 4; nt++)
        acc[mt][nt] = __builtin_amdgcn_mfma_f32_16x16x32_bf16(af[mt], bf[nt], acc[mt][nt], 0, 0, 0);
  }

  // ---- epilogue: C element (m = row0+wm+mt*16+quad*4+reg, n = col0+wn+nt*16+l15)
  int cols[4];
  float bvs[4];
#pragma unroll
  for (int nt = 0; nt < 4; nt++) {
    cols[nt] = col0 + wn + nt * 16 + l15;
    bvs[nt]  = bias[cols[nt]] * ((MODE == 0) ? scale : 1.0f);
  }

  if constexpr (MODE == 0) {
    unsigned short* Y = (unsigned short*)Yv;
#pragma unroll
    for (int mt = 0; mt < 4; mt++)
#pragma unroll
      for (int r = 0; r < 4; r++) {
        const int m = row0 + wm + mt * 16 + quad * 4 + r;
        const int bb = m >> 11, s = m & 2047;
#pragma unroll
        for (int nt = 0; nt < 4; nt++) {
          const int h = cols[nt] >> 6, d = cols[nt] & 63;
          Y[(((size_t)(bb * NH + h)) * S_LEN + s) * HD + d] =
              f2bf(acc[mt][nt][r] * scale + bvs[nt]);
        }
      }
  } else if constexpr (MODE == 2) {
    // per-wave 64x64 transpose through LDS, 8-elem-chunk XOR swizzle
    __shared__ unsigned short T[4][64][64];
#pragma unroll
    for (int mt = 0; mt < 4; mt++)
#pragma unroll
      for (int r = 0; r < 4; r++) {
        const int sl = mt * 16 + quad * 4 + r;  // wave-local row (s)
        const int cch = sl >> 3;
#pragma unroll
        for (int nt = 0; nt < 4; nt++) {
          const int dl = nt * 16 + l15;         // wave-local col (d)
          const int slot = cch ^ (dl & 7);
          T[w][dl][slot * 8 + (sl & 7)] = f2bf(acc[mt][nt][r] + bvs[nt]);
        }
      }
    asm volatile("s_waitcnt lgkmcnt(0)" ::: "memory");
    unsigned short* Y = (unsigned short*)Yv;
#pragma unroll
    for (int j = 0; j < 8; j++) {
      const int cid = j * 64 + lane;
      const int dl = cid >> 3;              // 0..63
      const int c  = cid & 7;               // s-chunk
      const int slot = c ^ (dl & 7);
      short8 v = *(const short8*)&T[w][dl][slot * 8];
      const int col = col0 + wn + dl;       // global n
      const int h = col >> 6, d = col & 63;
      const int m = row0 + wm + c * 8;      // global s base (8 consecutive)
      const int bb = m >> 11, s = m & 2047;
      *(short8*)&Y[(((size_t)(bb * NH + h)) * HD + d) * S_LEN + s] = v;
    }
  } else {  // MODE 3: fp32 row-major
    float* Y = (float*)Yv;
#pragma unroll
    for (int mt = 0; mt < 4; mt++)
#pragma unroll
      for (int r = 0; r < 4; r++) {
        const int m = row0 + wm + mt * 16 + quad * 4 + r;
#pragma unroll
        for (int nt = 0; nt < 4; nt++)
          Y[(size_t)m * D_MODEL + cols[nt]] = acc[mt][nt][r] + bvs[nt];
      }
  }
}

__global__ __launch_bounds__(256) void gemm_qk(const unsigned short* q16, const unsigned short* k16,
                                               const unsigned short* wq, const unsigned short* wk,
                                               const float* bq, const float* bk,
                                               unsigned short* Q, unsigned short* K) {
  const bool z = (blockIdx.z != 0);
  gemm_body<0>(z ? k16 : q16, z ? wk : wq, z ? bk : bq, z ? (void*)K : (void*)Q,
               z ? 1.0f : 0.125f);
}

__global__ __launch_bounds__(256) void gemm_v(const unsigned short* v16, const unsigned short* wv,
                                              const float* bv, unsigned short* Vt) {
  gemm_body<2>(v16, wv, bv, Vt, 1.0f);
}

__global__ __launch_bounds__(256) void gemm_o(const unsigned short* o16, const unsigned short* wo,
                                              const float* bo, float* out) {
  gemm_body<3>(o16, wo, bo, out, 1.0f);
}

// ---------------- Flash attention (MFMA bf16), round-2 verified ----------------
__global__ __launch_bounds__(256) void attn_kernel(
    const unsigned short* __restrict__ Qh, const unsigned short* __restrict__ Kh,
    const unsigned short* __restrict__ Vt, unsigned short* __restrict__ O) {
  const int qb = blockIdx.x;
  const int h  = blockIdx.y;
  const int bb = blockIdx.z;
  const int tid = threadIdx.x;
  const int w = tid >> 6, lane = tid & 63;
  const int l15 = lane & 15, quad = lane >> 4;

  __shared__ unsigned short Ks[64][72];
  __shared__ unsigned short Vs[64][72];
  __shared__ unsigned short Ps[4][32][72];

  const size_t bh = (size_t)(bb * NH + h);
  const unsigned short* Qp = Qh + bh * S_LEN * HD;
  const unsigned short* Kp = Kh + bh * S_LEN * HD;
  const unsigned short* Vp = Vt + bh * (size_t)HD * S_LEN;

  short8 qf[2][2];
#pragma unroll
  for (int qnt = 0; qnt < 2; qnt++)
#pragma unroll
    for (int c = 0; c < 2; c++)
      qf[qnt][c] = *(const short8*)(Qp + (size_t)(qb * 128 + w * 32 + qnt * 16 + l15) * HD +
                                    c * 32 + quad * 8);

  float4a Oacc[2][4];
#pragma unroll
  for (int a = 0; a < 2; a++)
#pragma unroll
    for (int b = 0; b < 4; b++) Oacc[a][b] = (float4a){0.f, 0.f, 0.f, 0.f};
  float lp[2] = {0.f, 0.f};

  for (int kb = 0; kb < S_LEN; kb += 64) {
    __syncthreads();
    {
      const unsigned short* src = Kp + (size_t)kb * HD;
#pragma unroll
      for (int r = 0; r < 2; r++) {
        const int idx = tid + r * 256;
        const int row = idx >> 3, cb = (idx & 7) * 8;
        *(short8*)&Ks[row][cb] = *(const short8*)(src + row * HD + cb);
      }
      const unsigned short* vsrc = Vp + kb;
#pragma unroll
      for (int r = 0; r < 2; r++) {
        const int idx = tid + r * 256;
        const int row = idx >> 3, cb = (idx & 7) * 8;
        *(short8*)&Vs[row][cb] = *(const short8*)(vsrc + (size_t)row * S_LEN + cb);
      }
    }
    __syncthreads();

#pragma unroll
    for (int mt = 0; mt < 4; mt++) {
      short8 a0 = *(const short8*)&Ks[mt * 16 + l15][quad * 8];
      short8 a1 = *(const short8*)&Ks[mt * 16 + l15][32 + quad * 8];
#pragma unroll
      for (int qnt = 0; qnt < 2; qnt++) {
        float4a s = (float4a){0.f, 0.f, 0.f, 0.f};
        s = __builtin_amdgcn_mfma_f32_16x16x32_bf16(a0, qf[qnt][0], s, 0, 0, 0);
        s = __builtin_amdgcn_mfma_f32_16x16x32_bf16(a1, qf[qnt][1], s, 0, 0, 0);
        const float p0 = __expf(s[0]), p1 = __expf(s[1]);
        const float p2 = __expf(s[2]), p3 = __expf(s[3]);
        lp[qnt] += (p0 + p1) + (p2 + p3);
        const unsigned u01 = (unsigned)f2bf(p0) | ((unsigned)f2bf(p1) << 16);
        const unsigned u23 = (unsigned)f2bf(p2) | ((unsigned)f2bf(p3) << 16);
        unsigned short* prow = &Ps[w][qnt * 16 + l15][mt * 16 + quad * 4];
        *(unsigned*)(prow)     = u01;
        *(unsigned*)(prow + 2) = u23;
      }
    }
    asm volatile("s_waitcnt lgkmcnt(0)" ::: "memory");

#pragma unroll
    for (int c = 0; c < 2; c++) {
      short8 pa0 = *(const short8*)&Ps[w][l15][c * 32 + quad * 8];
      short8 pa1 = *(const short8*)&Ps[w][16 + l15][c * 32 + quad * 8];
#pragma unroll
      for (int nt = 0; nt < 4; nt++) {
        short8 vb = *(const short8*)&Vs[nt * 16 + l15][c * 32 + quad * 8];
        Oacc[0][nt] = __builtin_amdgcn_mfma_f32_16x16x32_bf16(pa0, vb, Oacc[0][nt], 0, 0, 0);
        Oacc[1][nt] = __builtin_amdgcn_mfma_f32_16x16x32_bf16(pa1, vb, Oacc[1][nt], 0, 0, 0);
      }
    }
  }

#pragma unroll
  for (int qnt = 0; qnt < 2; qnt++) {
    lp[qnt] += __shfl_xor(lp[qnt], 16);
    lp[qnt] += __shfl_xor(lp[qnt], 32);
  }

#pragma unroll
  for (int qnt = 0; qnt < 2; qnt++) {
#pragma unroll
    for (int reg = 0; reg < 4; reg++) {
      const float lsum = __shfl(lp[qnt], quad * 4 + reg);
      const float rinv = 1.0f / lsum;
      const int q = qb * 128 + w * 32 + qnt * 16 + quad * 4 + reg;
      unsigned short* orow = O + ((size_t)bb * S_LEN + q) * D_MODEL + h * HD;
#pragma unroll
      for (int nt = 0; nt < 4; nt++)
        orow[nt * 16 + l15] = f2bf(Oacc[qnt][nt][reg] * rinv);
    }
  }
}

extern "C" void kernel_launch(void* const* d_in, const int* in_sizes, int n_in,
                              void* d_out, int out_size, void* d_ws, size_t ws_size,
                              hipStream_t stream) {
  const float* query = (const float*)d_in[0];
  const float* key   = (const float*)d_in[1];
  const float* value = (const float*)d_in[2];
  const float* Wq = (const float*)d_in[3];
  const float* bq = (const float*)d_in[4];
  const float* Wk = (const float*)d_in[5];
  const float* bk = (const float*)d_in[6];
  const float* Wv = (const float*)d_in[7];
  const float* bv = (const float*)d_in[8];
  const float* Wo = (const float*)d_in[9];
  const float* bo = (const float*)d_in[10];
  float* out = (float*)d_out;

  char* ws = (char*)d_ws;
  const size_t MB = 1024 * 1024;
  unsigned short* xq16 = (unsigned short*)(ws + 0 * MB);   // 8 MB each
  unsigned short* xk16 = (unsigned short*)(ws + 8 * MB);
  unsigned short* xv16 = (unsigned short*)(ws + 16 * MB);
  unsigned short* wq16 = (unsigned short*)(ws + 24 * MB);  // 2 MB each
  unsigned short* wk16 = (unsigned short*)(ws + 26 * MB);
  unsigned short* wv16 = (unsigned short*)(ws + 28 * MB);
  unsigned short* wo16 = (unsigned short*)(ws + 30 * MB);
  unsigned short* qbuf = (unsigned short*)(ws + 32 * MB);  // 8 MB each
  unsigned short* kbuf = (unsigned short*)(ws + 40 * MB);
  unsigned short* vtbuf = (unsigned short*)(ws + 48 * MB);
  unsigned short* obuf = (unsigned short*)(ws + 56 * MB);

  ConvArgs ca;
  const int NX = ROWS * D_MODEL, NW = D_MODEL * D_MODEL;
  ca.s[0] = query; ca.d[0] = xq16; ca.n[0] = NX;
  ca.s[1] = key;   ca.d[1] = xk16; ca.n[1] = NX;
  ca.s[2] = value; ca.d[2] = xv16; ca.n[2] = NX;
  ca.s[3] = Wq;    ca.d[3] = wq16; ca.n[3] = NW;
  ca.s[4] = Wk;    ca.d[4] = wk16; ca.n[4] = NW;
  ca.s[5] = Wv;    ca.d[5] = wv16; ca.n[5] = NW;
  ca.s[6] = Wo;    ca.d[6] = wo16; ca.n[6] = NW;
  hipLaunchKernelGGL(convert_bf16, dim3(NX / 2048, 7), dim3(256), 0, stream, ca);

  dim3 gqk(ROWS / 128, D_MODEL / 128, 2);  // (32, 8, 2)
  hipLaunchKernelGGL(gemm_qk, gqk, dim3(256), 0, stream,
                     xq16, xk16, wq16, wk16, bq, bk, qbuf, kbuf);
  dim3 gg(ROWS / 128, D_MODEL / 128);      // (32, 8)
  hipLaunchKernelGGL(gemm_v, gg, dim3(256), 0, stream, xv16, wv16, bv, vtbuf);

  dim3 ga(S_LEN / 128, NH, BATCH);         // (16, 16, 2)
  hipLaunchKernelGGL(attn_kernel, ga, dim3(256), 0, stream, qbuf, kbuf, vtbuf, obuf);

  hipLaunchKernelGGL(gemm_o, gg, dim3(256), 0, stream, obuf, wo16, bo, out);
}

// Round 4
// 243.104 us; speedup vs baseline: 9.9221x; 1.1235x over previous
//
#include <hip/hip_runtime.h>
#include <hip/hip_bf16.h>

// MHA: B=2, S=2048, D=1024, H=16, hd=64, fp32 in/out.
// Round 4: occupancy + LDS-conflict attack.
//   convert_bf16 : fp32 -> bf16 (3 X tensors + 4 weights)
//   gemm_qkv     : fused z={Q,K,V} MFMA GEMM, swizzled DMA LDS (768 blocks)
//   attn_kernel  : split-K x2 flash MFMA (1024 blocks, 4/CU), DMA-staged K/V,
//                  un-normalized fp32 partial O + l
//   merge_kernel : O = (O0+O1)/(l0+l1) -> bf16
//   gemm_o       : 64x128-tile MFMA GEMM -> fp32 d_out (512 blocks)

constexpr int D_MODEL = 1024;
constexpr int S_LEN   = 2048;
constexpr int BATCH   = 2;
constexpr int NH      = 16;
constexpr int HD      = 64;
constexpr int ROWS    = BATCH * S_LEN;  // 4096

typedef __attribute__((ext_vector_type(8))) short short8;
typedef __attribute__((ext_vector_type(4))) float float4a;

static __device__ __forceinline__ unsigned short f2bf(float f) {
  union { float f; unsigned u; } v{f};
  unsigned r = v.u + 0x7FFFu + ((v.u >> 16) & 1u);  // RNE
  return (unsigned short)(r >> 16);
}

// async 16B/lane global -> LDS (per-lane global addr, wave-uniform LDS base + lane*16)
static __device__ __forceinline__ void async16(const void* g, void* l) {
  __builtin_amdgcn_global_load_lds(
      (const __attribute__((address_space(1))) unsigned int*)g,
      (__attribute__((address_space(3))) unsigned int*)l, 16, 0, 0);
}

// ---------------- fp32 -> bf16 convert ----------------
struct ConvArgs { const float* s[7]; unsigned short* d[7]; int n[7]; };

__global__ __launch_bounds__(256) void convert_bf16(ConvArgs a) {
  const int which = blockIdx.y;
  const int i = (blockIdx.x * 256 + threadIdx.x) * 8;
  if (i >= a.n[which]) return;
  const float4* s = (const float4*)(a.s[which] + i);
  float4 x = s[0], y = s[1];
  unsigned short t[8] = {f2bf(x.x), f2bf(x.y), f2bf(x.z), f2bf(x.w),
                         f2bf(y.x), f2bf(y.y), f2bf(y.z), f2bf(y.w)};
  *(short8*)(a.d[which] + i) = *(short8*)t;
}

// ---------------- MFMA bf16 GEMM: Y = A @ W^T (+bias) ----------------
// A: [ROWS, 1024] bf16 row-major. W: [1024, 1024] bf16 row-major ([n][k]).
// BM x 128 block tile, BK=32. LDS slot swizzle: slot(r,c)=r*4+((c+(r>>1))&3),
// DMA-staged (coalesced global, phase-conflict-free b128 reads).
// MODE 0: bf16 head-major [B,H,S,64], value = (acc + bias)*scale
// MODE 2: bf16 V^T [B,H,64,S]  (XOR-swizzled LDS transpose epilogue)
// MODE 3: fp32 row-major [ROWS, 1024]
template <int MODE, int BM>
static __device__ __forceinline__ void gemm_body(
    const unsigned short* __restrict__ A, const unsigned short* __restrict__ W,
    const float* __restrict__ bias, void* __restrict__ Yv, float scale,
    unsigned short* As, unsigned short* Bs, unsigned short* Tb) {
  constexpr int NT = (BM == 128) ? 4 : 2;
  const int tid = threadIdx.x;
  const int w = tid >> 6, lane = tid & 63;
  const int l15 = lane & 15, quad = lane >> 4;
  const int row0 = blockIdx.x * BM, col0 = blockIdx.y * 128;
  const int wm = (BM == 128) ? (w & 1) * 64 : 0;
  const int wn = (BM == 128) ? (w >> 1) * 64 : w * 32;

  float4a acc[4][NT];
#pragma unroll
  for (int i = 0; i < 4; i++)
#pragma unroll
    for (int j = 0; j < NT; j++) acc[i][j] = (float4a){0.f, 0.f, 0.f, 0.f};

  // fragment-read swizzles (mt/nt-independent)
  const int swA = (quad + (wm >> 1) + (l15 >> 1)) & 3;
  const int swB = (quad + (wn >> 1) + (l15 >> 1)) & 3;

  for (int kt = 0; kt < D_MODEL; kt += 32) {
    __syncthreads();  // prior ds_reads done before DMA overwrite
    // B staging: 8 calls (2/wave), 128 rows
#pragma unroll
    for (int j = 0; j < 2; j++) {
      const int i = w * 2 + j;
      const int r = i * 16 + (lane >> 2);
      const int c = ((lane & 3) - (r >> 1)) & 3;
      async16(W + (size_t)(col0 + r) * D_MODEL + kt + c * 8, (char*)Bs + i * 1024);
    }
    // A staging
    if constexpr (BM == 128) {
#pragma unroll
      for (int j = 0; j < 2; j++) {
        const int i = w * 2 + j;
        const int r = i * 16 + (lane >> 2);
        const int c = ((lane & 3) - (r >> 1)) & 3;
        async16(A + (size_t)(row0 + r) * D_MODEL + kt + c * 8, (char*)As + i * 1024);
      }
    } else {
      const int r = w * 16 + (lane >> 2);
      const int c = ((lane & 3) - (r >> 1)) & 3;
      async16(A + (size_t)(row0 + r) * D_MODEL + kt + c * 8, (char*)As + w * 1024);
    }
    __syncthreads();  // drain vmcnt -> tiles resident

    short8 af[4], bf[NT];
#pragma unroll
    for (int mt = 0; mt < 4; mt++) {
      const int r = wm + mt * 16 + l15;
      af[mt] = *(const short8*)&As[(r * 4 + swA) * 8];
    }
#pragma unroll
    for (int nt = 0; nt < NT; nt++) {
      const int r = wn + nt * 16 + l15;
      bf[nt] = *(const short8*)&Bs[(r * 4 + swB) * 8];
    }
#pragma unroll
    for (int mt = 0; mt < 4; mt++)
#pragma unroll
      for (int nt = 0; nt < NT; nt++)
        acc[mt][nt] = __builtin_amdgcn_mfma_f32_16x16x32_bf16(af[mt], bf[nt], acc[mt][nt], 0, 0, 0);
  }

  int cols[NT];
  float bvs[NT];
#pragma unroll
  for (int nt = 0; nt < NT; nt++) {
    cols[nt] = col0 + wn + nt * 16 + l15;
    bvs[nt]  = bias[cols[nt]] * ((MODE == 0) ? scale : 1.0f);
  }

  if constexpr (MODE == 0) {
    unsigned short* Y = (unsigned short*)Yv;
#pragma unroll
    for (int mt = 0; mt < 4; mt++)
#pragma unroll
      for (int r = 0; r < 4; r++) {
        const int m = row0 + wm + mt * 16 + quad * 4 + r;
        const int bb = m >> 11, s = m & 2047;
#pragma unroll
        for (int nt = 0; nt < NT; nt++) {
          const int h = cols[nt] >> 6, d = cols[nt] & 63;
          Y[(((size_t)(bb * NH + h)) * S_LEN + s) * HD + d] =
              f2bf(acc[mt][nt][r] * scale + bvs[nt]);
        }
      }
  } else if constexpr (MODE == 2) {
    unsigned short* T = Tb + w * 64 * 64;  // per-wave 64x64 transpose buffer
#pragma unroll
    for (int mt = 0; mt < 4; mt++)
#pragma unroll
      for (int r = 0; r < 4; r++) {
        const int sl = mt * 16 + quad * 4 + r;  // wave-local row (s)
        const int cch = sl >> 3;
#pragma unroll
        for (int nt = 0; nt < NT; nt++) {
          const int dl = cols[nt] - col0 - wn;  // nt*16+l15
          const int slot = cch ^ (dl & 7);
          T[dl * 64 + slot * 8 + (sl & 7)] = f2bf(acc[mt][nt][r] + bvs[nt]);
        }
      }
    asm volatile("s_waitcnt lgkmcnt(0)" ::: "memory");
    unsigned short* Y = (unsigned short*)Yv;
#pragma unroll
    for (int j = 0; j < 8; j++) {
      const int cid = j * 64 + lane;
      const int dl = cid >> 3;
      const int c  = cid & 7;
      const int slot = c ^ (dl & 7);
      short8 v = *(const short8*)&T[dl * 64 + slot * 8];
      const int col = col0 + wn + dl;
      const int h = col >> 6, d = col & 63;
      const int m = row0 + wm + c * 8;
      const int bb = m >> 11, s = m & 2047;
      *(short8*)&Y[(((size_t)(bb * NH + h)) * HD + d) * S_LEN + s] = v;
    }
  } else {  // MODE 3
    float* Y = (float*)Yv;
#pragma unroll
    for (int mt = 0; mt < 4; mt++)
#pragma unroll
      for (int r = 0; r < 4; r++) {
        const int m = row0 + wm + mt * 16 + quad * 4 + r;
#pragma unroll
        for (int nt = 0; nt < NT; nt++)
          Y[(size_t)m * D_MODEL + cols[nt]] = acc[mt][nt][r] + bvs[nt];
      }
  }
}

__global__ __launch_bounds__(256) void gemm_qkv(
    const unsigned short* xq, const unsigned short* xk, const unsigned short* xv,
    const unsigned short* wq, const unsigned short* wk, const unsigned short* wv,
    const float* bq, const float* bk, const float* bv,
    unsigned short* Q, unsigned short* K, unsigned short* Vt) {
  __shared__ unsigned short As[128 * 32];
  __shared__ unsigned short Bs[128 * 32];
  __shared__ unsigned short Tb[4 * 64 * 64];
  const int z = blockIdx.z;
  if (z == 0)      gemm_body<0, 128>(xq, wq, bq, Q,  0.125f, As, Bs, Tb);
  else if (z == 1) gemm_body<0, 128>(xk, wk, bk, K,  1.0f,   As, Bs, Tb);
  else             gemm_body<2, 128>(xv, wv, bv, Vt, 1.0f,   As, Bs, Tb);
}

__global__ __launch_bounds__(256) void gemm_o(const unsigned short* o16, const unsigned short* wo,
                                              const float* bo, float* out) {
  __shared__ unsigned short As[64 * 32];
  __shared__ unsigned short Bs[128 * 32];
  gemm_body<3, 64>(o16, wo, bo, out, 1.0f, As, Bs, nullptr);
}

// ---------------- Flash attention, split-K x2, DMA-staged ----------------
// grid (16, 16, 4): qb, h, z = bb*2 + split. 256 thr = 4 waves, wave w owns
// 32 q rows. Keys [split*1024, +1024) in 16 tiles of 64. Partial O (fp32,
// un-normalized) + partial l written per split; merged later.
__global__ __launch_bounds__(256) void attn_kernel(
    const unsigned short* __restrict__ Qh, const unsigned short* __restrict__ Kh,
    const unsigned short* __restrict__ Vt, float* __restrict__ Op,
    float* __restrict__ Lp) {
  const int qb = blockIdx.x;
  const int h  = blockIdx.y;
  const int bb = blockIdx.z >> 1, sp = blockIdx.z & 1;
  const int tid = threadIdx.x;
  const int w = tid >> 6, lane = tid & 63;
  const int l15 = lane & 15, quad = lane >> 4;

  __shared__ unsigned short Ks[64 * 64];   // slot(r,c)=r*8+((c+r)&7), 16B chunks
  __shared__ unsigned short Vs[64 * 64];   // V^T tile, same swizzle on d-rows
  __shared__ unsigned short Ps[4][32][72];

  const size_t bh = (size_t)(bb * NH + h);
  const unsigned short* Qp = Qh + bh * S_LEN * HD;
  const unsigned short* Kp = Kh + bh * S_LEN * HD;
  const unsigned short* Vp = Vt + bh * (size_t)HD * S_LEN;

  short8 qf[2][2];
#pragma unroll
  for (int qnt = 0; qnt < 2; qnt++)
#pragma unroll
    for (int c = 0; c < 2; c++)
      qf[qnt][c] = *(const short8*)(Qp + (size_t)(qb * 128 + w * 32 + qnt * 16 + l15) * HD +
                                    c * 32 + quad * 8);

  float4a Oacc[2][4];
#pragma unroll
  for (int a = 0; a < 2; a++)
#pragma unroll
    for (int b = 0; b < 4; b++) Oacc[a][b] = (float4a){0.f, 0.f, 0.f, 0.f};
  float lp[2] = {0.f, 0.f};

  const int sw0 = (quad + l15) & 7;        // K-frag chunk swizzles
  const int sw1 = (quad + 4 + l15) & 7;

  for (int kb = sp * 1024; kb < sp * 1024 + 1024; kb += 64) {
    __syncthreads();
#pragma unroll
    for (int j = 0; j < 2; j++) {
      const int i = w * 2 + j;
      const int r = i * 8 + (lane >> 3);
      const int c = ((lane & 7) - r) & 7;
      async16(Kp + (size_t)(kb + r) * HD + c * 8, (char*)Ks + i * 1024);
      async16(Vp + (size_t)r * S_LEN + kb + c * 8, (char*)Vs + i * 1024);
    }
    __syncthreads();

    // S^T = K·Q^T, exp -> P (bf16) into per-wave LDS (b64 writes)
#pragma unroll
    for (int mt = 0; mt < 4; mt++) {
      const int rb = (mt * 16 + l15) * 8;
      short8 a0 = *(const short8*)&Ks[(rb + sw0) * 8];
      short8 a1 = *(const short8*)&Ks[(rb + sw1) * 8];
#pragma unroll
      for (int qnt = 0; qnt < 2; qnt++) {
        float4a s = (float4a){0.f, 0.f, 0.f, 0.f};
        s = __builtin_amdgcn_mfma_f32_16x16x32_bf16(a0, qf[qnt][0], s, 0, 0, 0);
        s = __builtin_amdgcn_mfma_f32_16x16x32_bf16(a1, qf[qnt][1], s, 0, 0, 0);
        const float p0 = __expf(s[0]), p1 = __expf(s[1]);
        const float p2 = __expf(s[2]), p3 = __expf(s[3]);
        lp[qnt] += (p0 + p1) + (p2 + p3);
        uint2 pk;
        pk.x = (unsigned)f2bf(p0) | ((unsigned)f2bf(p1) << 16);
        pk.y = (unsigned)f2bf(p2) | ((unsigned)f2bf(p3) << 16);
        *(uint2*)&Ps[w][qnt * 16 + l15][mt * 16 + quad * 4] = pk;
      }
    }
    asm volatile("s_waitcnt lgkmcnt(0)" ::: "memory");  // P write->read, same wave

    // O += P·V
#pragma unroll
    for (int c = 0; c < 2; c++) {
      short8 pa0 = *(const short8*)&Ps[w][l15][c * 32 + quad * 8];
      short8 pa1 = *(const short8*)&Ps[w][16 + l15][c * 32 + quad * 8];
      const int vsw = (c * 4 + quad + l15) & 7;
#pragma unroll
      for (int nt = 0; nt < 4; nt++) {
        short8 vb = *(const short8*)&Vs[((nt * 16 + l15) * 8 + vsw) * 8];
        Oacc[0][nt] = __builtin_amdgcn_mfma_f32_16x16x32_bf16(pa0, vb, Oacc[0][nt], 0, 0, 0);
        Oacc[1][nt] = __builtin_amdgcn_mfma_f32_16x16x32_bf16(pa1, vb, Oacc[1][nt], 0, 0, 0);
      }
    }
  }

  // reduce l over the 4 quads
#pragma unroll
  for (int qnt = 0; qnt < 2; qnt++) {
    lp[qnt] += __shfl_xor(lp[qnt], 16);
    lp[qnt] += __shfl_xor(lp[qnt], 32);
  }
  if (quad == 0) {
#pragma unroll
    for (int qnt = 0; qnt < 2; qnt++) {
      const int q = qb * 128 + w * 32 + qnt * 16 + l15;
      Lp[(size_t)sp * ROWS * NH + ((size_t)bb * S_LEN + q) * NH + h] = lp[qnt];
    }
  }

  float* Ob = Op + (size_t)sp * ROWS * D_MODEL;
#pragma unroll
  for (int qnt = 0; qnt < 2; qnt++) {
#pragma unroll
    for (int reg = 0; reg < 4; reg++) {
      const int q = qb * 128 + w * 32 + qnt * 16 + quad * 4 + reg;
      float* orow = Ob + ((size_t)bb * S_LEN + q) * D_MODEL + h * HD;
#pragma unroll
      for (int nt = 0; nt < 4; nt++)
        orow[nt * 16 + l15] = Oacc[qnt][nt][reg];
    }
  }
}

// ---------------- merge partials: obuf = (O0+O1)/(l0+l1) -> bf16 ----------------
__global__ __launch_bounds__(256) void merge_kernel(const float* __restrict__ Op,
                                                    const float* __restrict__ Lp,
                                                    unsigned short* __restrict__ obuf) {
  const int e = (blockIdx.x * 256 + threadIdx.x) * 8;
  const int row = e >> 10, h = (e & 1023) >> 6;
  const float l = Lp[(size_t)row * NH + h] + Lp[(size_t)ROWS * NH + (size_t)row * NH + h];
  const float rinv = 1.0f / l;
  const float4* p0 = (const float4*)(Op + e);
  const float4* p1 = (const float4*)(Op + (size_t)ROWS * D_MODEL + e);
  float4 a = p0[0], b = p0[1], c = p1[0], d = p1[1];
  unsigned short t[8] = {
      f2bf((a.x + c.x) * rinv), f2bf((a.y + c.y) * rinv),
      f2bf((a.z + c.z) * rinv), f2bf((a.w + c.w) * rinv),
      f2bf((b.x + d.x) * rinv), f2bf((b.y + d.y) * rinv),
      f2bf((b.z + d.z) * rinv), f2bf((b.w + d.w) * rinv)};
  *(short8*)(obuf + e) = *(short8*)t;
}

extern "C" void kernel_launch(void* const* d_in, const int* in_sizes, int n_in,
                              void* d_out, int out_size, void* d_ws, size_t ws_size,
                              hipStream_t stream) {
  const float* query = (const float*)d_in[0];
  const float* key   = (const float*)d_in[1];
  const float* value = (const float*)d_in[2];
  const float* Wq = (const float*)d_in[3];
  const float* bq = (const float*)d_in[4];
  const float* Wk = (const float*)d_in[5];
  const float* bk = (const float*)d_in[6];
  const float* Wv = (const float*)d_in[7];
  const float* bv = (const float*)d_in[8];
  const float* Wo = (const float*)d_in[9];
  const float* bo = (const float*)d_in[10];
  float* out = (float*)d_out;

  char* ws = (char*)d_ws;
  const size_t MB = 1024 * 1024;
  // [0,8) xq16 | [8,16) xk16 | [16,24) xv16 | [24,26) wq | [26,28) wk | [28,30) wv
  // [32,40) qbuf (later obuf) | [40,48) kbuf | [48,56) vtbuf | [56,58) wo16 | [58,58.5) Lp
  // After gemm_qkv, [0,16)=Op0 and [16,32)=Op1 reuse the dead x/w region.
  unsigned short* xq16 = (unsigned short*)(ws + 0 * MB);
  unsigned short* xk16 = (unsigned short*)(ws + 8 * MB);
  unsigned short* xv16 = (unsigned short*)(ws + 16 * MB);
  unsigned short* wq16 = (unsigned short*)(ws + 24 * MB);
  unsigned short* wk16 = (unsigned short*)(ws + 26 * MB);
  unsigned short* wv16 = (unsigned short*)(ws + 28 * MB);
  unsigned short* qbuf  = (unsigned short*)(ws + 32 * MB);
  unsigned short* kbuf  = (unsigned short*)(ws + 40 * MB);
  unsigned short* vtbuf = (unsigned short*)(ws + 48 * MB);
  unsigned short* wo16  = (unsigned short*)(ws + 56 * MB);
  float* Lp  = (float*)(ws + 58 * MB);
  float* Op  = (float*)(ws + 0 * MB);    // 2 x 16 MB partials (aliases dead x/w)
  unsigned short* obuf = qbuf;            // aliases qbuf (dead after attn)

  ConvArgs ca;
  const int NX = ROWS * D_MODEL, NW = D_MODEL * D_MODEL;
  ca.s[0] = query; ca.d[0] = xq16; ca.n[0] = NX;
  ca.s[1] = key;   ca.d[1] = xk16; ca.n[1] = NX;
  ca.s[2] = value; ca.d[2] = xv16; ca.n[2] = NX;
  ca.s[3] = Wq;    ca.d[3] = wq16; ca.n[3] = NW;
  ca.s[4] = Wk;    ca.d[4] = wk16; ca.n[4] = NW;
  ca.s[5] = Wv;    ca.d[5] = wv16; ca.n[5] = NW;
  ca.s[6] = Wo;    ca.d[6] = wo16; ca.n[6] = NW;
  hipLaunchKernelGGL(convert_bf16, dim3(NX / 2048, 7), dim3(256), 0, stream, ca);

  dim3 gqkv(ROWS / 128, D_MODEL / 128, 3);  // (32, 8, 3) = 768 blocks
  hipLaunchKernelGGL(gemm_qkv, gqkv, dim3(256), 0, stream,
                     xq16, xk16, xv16, wq16, wk16, wv16, bq, bk, bv,
                     qbuf, kbuf, vtbuf);

  dim3 ga(S_LEN / 128, NH, BATCH * 2);      // (16, 16, 4) = 1024 blocks
  hipLaunchKernelGGL(attn_kernel, ga, dim3(256), 0, stream, qbuf, kbuf, vtbuf, Op, Lp);

  hipLaunchKernelGGL(merge_kernel, dim3(ROWS * D_MODEL / 2048), dim3(256), 0, stream,
                     Op, Lp, obuf);

  dim3 go(ROWS / 64, D_MODEL / 128);        // (64, 8) = 512 blocks
  hipLaunchKernelGGL(gemm_o, go, dim3(256), 0, stream, obuf, wo16, bo, out);
}

// Round 5
// 236.135 us; speedup vs baseline: 10.2149x; 1.0295x over previous
//
#include <hip/hip_runtime.h>
#include <hip/hip_bf16.h>

// MHA: B=2, S=2048, D=1024, H=16, hd=64, fp32 in/out.
// Round 5: attn VALU-pipe cut.
//   - l accumulated via MFMA with all-ones B fragment (no VALU adds/shuffles)
//   - packed bf16 convert (v_cvt_pk_bf16_f32, guarded) for P and partials
//   - exp2 with log2e folded into Q projection scale
//   - bf16 un-normalized partial O (halves split-K partial traffic)

constexpr int D_MODEL = 1024;
constexpr int S_LEN   = 2048;
constexpr int BATCH   = 2;
constexpr int NH      = 16;
constexpr int HD      = 64;
constexpr int ROWS    = BATCH * S_LEN;  // 4096

typedef __attribute__((ext_vector_type(8))) short short8;
typedef __attribute__((ext_vector_type(4))) float float4a;

static __device__ __forceinline__ unsigned short f2bf(float f) {
  union { float f; unsigned u; } v{f};
  unsigned r = v.u + 0x7FFFu + ((v.u >> 16) & 1u);  // RNE
  return (unsigned short)(r >> 16);
}

// pack two fp32 -> bf16x2 (RNE), single instruction on gfx950
static __device__ __forceinline__ unsigned pack_bf16(float a, float b) {
#if __has_builtin(__builtin_amdgcn_cvt_pk_bf16_f32)
  typedef __attribute__((ext_vector_type(2))) __bf16 bf16x2;
  union { bf16x2 v; unsigned u; } c;
  c.v = __builtin_amdgcn_cvt_pk_bf16_f32(a, b);
  return c.u;
#else
  return (unsigned)f2bf(a) | ((unsigned)f2bf(b) << 16);
#endif
}

static __device__ __forceinline__ float bf2f(unsigned short u) {
  union { unsigned u; float f; } v;
  v.u = (unsigned)u << 16;
  return v.f;
}

// async 16B/lane global -> LDS
static __device__ __forceinline__ void async16(const void* g, void* l) {
  __builtin_amdgcn_global_load_lds(
      (const __attribute__((address_space(1))) unsigned int*)g,
      (__attribute__((address_space(3))) unsigned int*)l, 16, 0, 0);
}

// ---------------- fp32 -> bf16 convert ----------------
struct ConvArgs { const float* s[7]; unsigned short* d[7]; int n[7]; };

__global__ __launch_bounds__(256) void convert_bf16(ConvArgs a) {
  const int which = blockIdx.y;
  const int i = (blockIdx.x * 256 + threadIdx.x) * 8;
  if (i >= a.n[which]) return;
  const float4* s = (const float4*)(a.s[which] + i);
  float4 x = s[0], y = s[1];
  unsigned t[4] = {pack_bf16(x.x, x.y), pack_bf16(x.z, x.w),
                   pack_bf16(y.x, y.y), pack_bf16(y.z, y.w)};
  *(short8*)(a.d[which] + i) = *(short8*)t;
}

// ---------------- MFMA bf16 GEMM: Y = A @ W^T (+bias) ----------------
// BM x 128 block tile, BK=32. DMA-staged swizzled LDS.
// MODE 0: bf16 head-major [B,H,S,64], value = (acc + bias)*scale
// MODE 2: bf16 V^T [B,H,64,S]  (XOR-swizzled LDS transpose epilogue)
// MODE 3: fp32 row-major [ROWS, 1024]
template <int MODE, int BM>
static __device__ __forceinline__ void gemm_body(
    const unsigned short* __restrict__ A, const unsigned short* __restrict__ W,
    const float* __restrict__ bias, void* __restrict__ Yv, float scale,
    unsigned short* As, unsigned short* Bs, unsigned short* Tb) {
  constexpr int NT = (BM == 128) ? 4 : 2;
  const int tid = threadIdx.x;
  const int w = tid >> 6, lane = tid & 63;
  const int l15 = lane & 15, quad = lane >> 4;
  const int row0 = blockIdx.x * BM, col0 = blockIdx.y * 128;
  const int wm = (BM == 128) ? (w & 1) * 64 : 0;
  const int wn = (BM == 128) ? (w >> 1) * 64 : w * 32;

  float4a acc[4][NT];
#pragma unroll
  for (int i = 0; i < 4; i++)
#pragma unroll
    for (int j = 0; j < NT; j++) acc[i][j] = (float4a){0.f, 0.f, 0.f, 0.f};

  const int swA = (quad + (wm >> 1) + (l15 >> 1)) & 3;
  const int swB = (quad + (wn >> 1) + (l15 >> 1)) & 3;

  for (int kt = 0; kt < D_MODEL; kt += 32) {
    __syncthreads();
#pragma unroll
    for (int j = 0; j < 2; j++) {
      const int i = w * 2 + j;
      const int r = i * 16 + (lane >> 2);
      const int c = ((lane & 3) - (r >> 1)) & 3;
      async16(W + (size_t)(col0 + r) * D_MODEL + kt + c * 8, (char*)Bs + i * 1024);
    }
    if constexpr (BM == 128) {
#pragma unroll
      for (int j = 0; j < 2; j++) {
        const int i = w * 2 + j;
        const int r = i * 16 + (lane >> 2);
        const int c = ((lane & 3) - (r >> 1)) & 3;
        async16(A + (size_t)(row0 + r) * D_MODEL + kt + c * 8, (char*)As + i * 1024);
      }
    } else {
      const int r = w * 16 + (lane >> 2);
      const int c = ((lane & 3) - (r >> 1)) & 3;
      async16(A + (size_t)(row0 + r) * D_MODEL + kt + c * 8, (char*)As + w * 1024);
    }
    __syncthreads();

    short8 af[4], bf[NT];
#pragma unroll
    for (int mt = 0; mt < 4; mt++) {
      const int r = wm + mt * 16 + l15;
      af[mt] = *(const short8*)&As[(r * 4 + swA) * 8];
    }
#pragma unroll
    for (int nt = 0; nt < NT; nt++) {
      const int r = wn + nt * 16 + l15;
      bf[nt] = *(const short8*)&Bs[(r * 4 + swB) * 8];
    }
#pragma unroll
    for (int mt = 0; mt < 4; mt++)
#pragma unroll
      for (int nt = 0; nt < NT; nt++)
        acc[mt][nt] = __builtin_amdgcn_mfma_f32_16x16x32_bf16(af[mt], bf[nt], acc[mt][nt], 0, 0, 0);
  }

  int cols[NT];
  float bvs[NT];
#pragma unroll
  for (int nt = 0; nt < NT; nt++) {
    cols[nt] = col0 + wn + nt * 16 + l15;
    bvs[nt]  = bias[cols[nt]] * ((MODE == 0) ? scale : 1.0f);
  }

  if constexpr (MODE == 0) {
    unsigned short* Y = (unsigned short*)Yv;
#pragma unroll
    for (int mt = 0; mt < 4; mt++)
#pragma unroll
      for (int r = 0; r < 4; r++) {
        const int m = row0 + wm + mt * 16 + quad * 4 + r;
        const int bb = m >> 11, s = m & 2047;
#pragma unroll
        for (int nt = 0; nt < NT; nt++) {
          const int h = cols[nt] >> 6, d = cols[nt] & 63;
          Y[(((size_t)(bb * NH + h)) * S_LEN + s) * HD + d] =
              f2bf(acc[mt][nt][r] * scale + bvs[nt]);
        }
      }
  } else if constexpr (MODE == 2) {
    unsigned short* T = Tb + w * 64 * 64;
#pragma unroll
    for (int mt = 0; mt < 4; mt++)
#pragma unroll
      for (int r = 0; r < 4; r++) {
        const int sl = mt * 16 + quad * 4 + r;
        const int cch = sl >> 3;
#pragma unroll
        for (int nt = 0; nt < NT; nt++) {
          const int dl = cols[nt] - col0 - wn;
          const int slot = cch ^ (dl & 7);
          T[dl * 64 + slot * 8 + (sl & 7)] = f2bf(acc[mt][nt][r] + bvs[nt]);
        }
      }
    asm volatile("s_waitcnt lgkmcnt(0)" ::: "memory");
    unsigned short* Y = (unsigned short*)Yv;
#pragma unroll
    for (int j = 0; j < 8; j++) {
      const int cid = j * 64 + lane;
      const int dl = cid >> 3;
      const int c  = cid & 7;
      const int slot = c ^ (dl & 7);
      short8 v = *(const short8*)&T[dl * 64 + slot * 8];
      const int col = col0 + wn + dl;
      const int h = col >> 6, d = col & 63;
      const int m = row0 + wm + c * 8;
      const int bb = m >> 11, s = m & 2047;
      *(short8*)&Y[(((size_t)(bb * NH + h)) * HD + d) * S_LEN + s] = v;
    }
  } else {  // MODE 3
    float* Y = (float*)Yv;
#pragma unroll
    for (int mt = 0; mt < 4; mt++)
#pragma unroll
      for (int r = 0; r < 4; r++) {
        const int m = row0 + wm + mt * 16 + quad * 4 + r;
#pragma unroll
        for (int nt = 0; nt < NT; nt++)
          Y[(size_t)m * D_MODEL + cols[nt]] = acc[mt][nt][r] + bvs[nt];
      }
  }
}

__global__ __launch_bounds__(256) void gemm_qkv(
    const unsigned short* xq, const unsigned short* xk, const unsigned short* xv,
    const unsigned short* wq, const unsigned short* wk, const unsigned short* wv,
    const float* bq, const float* bk, const float* bv,
    unsigned short* Q, unsigned short* K, unsigned short* Vt) {
  __shared__ unsigned short As[128 * 32];
  __shared__ unsigned short Bs[128 * 32];
  __shared__ unsigned short Tb[4 * 64 * 64];
  const int z = blockIdx.z;
  // Q scale: 1/sqrt(64) * log2(e)  (softmax done in exp2 domain)
  if (z == 0)      gemm_body<0, 128>(xq, wq, bq, Q,  0.125f * 1.44269504f, As, Bs, Tb);
  else if (z == 1) gemm_body<0, 128>(xk, wk, bk, K,  1.0f,   As, Bs, Tb);
  else             gemm_body<2, 128>(xv, wv, bv, Vt, 1.0f,   As, Bs, Tb);
}

__global__ __launch_bounds__(256) void gemm_o(const unsigned short* o16, const unsigned short* wo,
                                              const float* bo, float* out) {
  __shared__ unsigned short As[64 * 32];
  __shared__ unsigned short Bs[128 * 32];
  gemm_body<3, 64>(o16, wo, bo, out, 1.0f, As, Bs, nullptr);
}

// ---------------- Flash attention, split-K x2, DMA-staged ----------------
// grid (16, 16, 4): qb, h, z = bb*2 + split. Wave w owns 32 q rows.
// P = exp2(S^T) (Q pre-scaled by log2e/8). l accumulated by MFMA with ones.
// Un-normalized bf16 partial O + fp32 l per split; merged later.
__global__ __launch_bounds__(256) void attn_kernel(
    const unsigned short* __restrict__ Qh, const unsigned short* __restrict__ Kh,
    const unsigned short* __restrict__ Vt, unsigned short* __restrict__ Op,
    float* __restrict__ Lp) {
  const int qb = blockIdx.x;
  const int h  = blockIdx.y;
  const int bb = blockIdx.z >> 1, sp = blockIdx.z & 1;
  const int tid = threadIdx.x;
  const int w = tid >> 6, lane = tid & 63;
  const int l15 = lane & 15, quad = lane >> 4;

  __shared__ unsigned short Ks[64 * 64];   // slot(r,c)=r*8+((c+r)&7), 16B chunks
  __shared__ unsigned short Vs[64 * 64];
  __shared__ unsigned short Ps[4][32][72];

  const size_t bh = (size_t)(bb * NH + h);
  const unsigned short* Qp = Qh + bh * S_LEN * HD;
  const unsigned short* Kp = Kh + bh * S_LEN * HD;
  const unsigned short* Vp = Vt + bh * (size_t)HD * S_LEN;

  short8 qf[2][2];
#pragma unroll
  for (int qnt = 0; qnt < 2; qnt++)
#pragma unroll
    for (int c = 0; c < 2; c++)
      qf[qnt][c] = *(const short8*)(Qp + (size_t)(qb * 128 + w * 32 + qnt * 16 + l15) * HD +
                                    c * 32 + quad * 8);

  // all-ones bf16 B fragment for l = P . 1
  unsigned short ob[8] = {0x3F80, 0x3F80, 0x3F80, 0x3F80, 0x3F80, 0x3F80, 0x3F80, 0x3F80};
  const short8 ones = *(short8*)ob;

  float4a Oacc[2][4];
#pragma unroll
  for (int a = 0; a < 2; a++)
#pragma unroll
    for (int b = 0; b < 4; b++) Oacc[a][b] = (float4a){0.f, 0.f, 0.f, 0.f};
  float4a Lacc[2] = {(float4a){0.f, 0.f, 0.f, 0.f}, (float4a){0.f, 0.f, 0.f, 0.f}};

  const int sw0 = (quad + l15) & 7;
  const int sw1 = (quad + 4 + l15) & 7;

  for (int kb = sp * 1024; kb < sp * 1024 + 1024; kb += 64) {
    __syncthreads();
#pragma unroll
    for (int j = 0; j < 2; j++) {
      const int i = w * 2 + j;
      const int r = i * 8 + (lane >> 3);
      const int c = ((lane & 7) - r) & 7;
      async16(Kp + (size_t)(kb + r) * HD + c * 8, (char*)Ks + i * 1024);
      async16(Vp + (size_t)r * S_LEN + kb + c * 8, (char*)Vs + i * 1024);
    }
    __syncthreads();

    // S^T = K·Q^T, p = exp2(s) -> P (bf16) into per-wave LDS
#pragma unroll
    for (int mt = 0; mt < 4; mt++) {
      const int rb = (mt * 16 + l15) * 8;
      short8 a0 = *(const short8*)&Ks[(rb + sw0) * 8];
      short8 a1 = *(const short8*)&Ks[(rb + sw1) * 8];
#pragma unroll
      for (int qnt = 0; qnt < 2; qnt++) {
        float4a s = (float4a){0.f, 0.f, 0.f, 0.f};
        s = __builtin_amdgcn_mfma_f32_16x16x32_bf16(a0, qf[qnt][0], s, 0, 0, 0);
        s = __builtin_amdgcn_mfma_f32_16x16x32_bf16(a1, qf[qnt][1], s, 0, 0, 0);
        uint2 pk;
        pk.x = pack_bf16(__builtin_amdgcn_exp2f(s[0]), __builtin_amdgcn_exp2f(s[1]));
        pk.y = pack_bf16(__builtin_amdgcn_exp2f(s[2]), __builtin_amdgcn_exp2f(s[3]));
        *(uint2*)&Ps[w][qnt * 16 + l15][mt * 16 + quad * 4] = pk;
      }
    }
    asm volatile("s_waitcnt lgkmcnt(0)" ::: "memory");  // P write->read, same wave

    // O += P·V ; l += P·1 (MFMA)
#pragma unroll
    for (int c = 0; c < 2; c++) {
      short8 pa0 = *(const short8*)&Ps[w][l15][c * 32 + quad * 8];
      short8 pa1 = *(const short8*)&Ps[w][16 + l15][c * 32 + quad * 8];
      Lacc[0] = __builtin_amdgcn_mfma_f32_16x16x32_bf16(pa0, ones, Lacc[0], 0, 0, 0);
      Lacc[1] = __builtin_amdgcn_mfma_f32_16x16x32_bf16(pa1, ones, Lacc[1], 0, 0, 0);
      const int vsw = (c * 4 + quad + l15) & 7;
#pragma unroll
      for (int nt = 0; nt < 4; nt++) {
        short8 vb = *(const short8*)&Vs[((nt * 16 + l15) * 8 + vsw) * 8];
        Oacc[0][nt] = __builtin_amdgcn_mfma_f32_16x16x32_bf16(pa0, vb, Oacc[0][nt], 0, 0, 0);
        Oacc[1][nt] = __builtin_amdgcn_mfma_f32_16x16x32_bf16(pa1, vb, Oacc[1][nt], 0, 0, 0);
      }
    }
  }

  // Lacc[qnt][reg] = l(q = qnt*16 + quad*4 + reg), identical across l15
  if (l15 == 0) {
#pragma unroll
    for (int qnt = 0; qnt < 2; qnt++)
#pragma unroll
      for (int reg = 0; reg < 4; reg++) {
        const int q = qb * 128 + w * 32 + qnt * 16 + quad * 4 + reg;
        Lp[(size_t)sp * ROWS * NH + ((size_t)bb * S_LEN + q) * NH + h] = Lacc[qnt][reg];
      }
  }

  unsigned short* Ob = Op + (size_t)sp * ROWS * D_MODEL;
#pragma unroll
  for (int qnt = 0; qnt < 2; qnt++) {
#pragma unroll
    for (int reg = 0; reg < 4; reg++) {
      const int q = qb * 128 + w * 32 + qnt * 16 + quad * 4 + reg;
      unsigned short* orow = Ob + ((size_t)bb * S_LEN + q) * D_MODEL + h * HD;
#pragma unroll
      for (int nt = 0; nt < 4; nt++)
        orow[nt * 16 + l15] = f2bf(Oacc[qnt][nt][reg]);
    }
  }
}

// ---------------- merge partials: obuf = (O0+O1)/(l0+l1) -> bf16 ----------------
__global__ __launch_bounds__(256) void merge_kernel(const unsigned short* __restrict__ Op,
                                                    const float* __restrict__ Lp,
                                                    unsigned short* __restrict__ obuf) {
  const int e = (blockIdx.x * 256 + threadIdx.x) * 8;
  const int row = e >> 10, h = (e & 1023) >> 6;
  const float l = Lp[(size_t)row * NH + h] + Lp[(size_t)ROWS * NH + (size_t)row * NH + h];
  const float rinv = 1.0f / l;
  short8 a = *(const short8*)(Op + e);
  short8 b = *(const short8*)(Op + (size_t)ROWS * D_MODEL + e);
  unsigned t[4];
#pragma unroll
  for (int i = 0; i < 4; i++) {
    const float v0 = (bf2f((unsigned short)a[2 * i]) + bf2f((unsigned short)b[2 * i])) * rinv;
    const float v1 = (bf2f((unsigned short)a[2 * i + 1]) + bf2f((unsigned short)b[2 * i + 1])) * rinv;
    t[i] = pack_bf16(v0, v1);
  }
  *(short8*)(obuf + e) = *(short8*)t;
}

extern "C" void kernel_launch(void* const* d_in, const int* in_sizes, int n_in,
                              void* d_out, int out_size, void* d_ws, size_t ws_size,
                              hipStream_t stream) {
  const float* query = (const float*)d_in[0];
  const float* key   = (const float*)d_in[1];
  const float* value = (const float*)d_in[2];
  const float* Wq = (const float*)d_in[3];
  const float* bq = (const float*)d_in[4];
  const float* Wk = (const float*)d_in[5];
  const float* bk = (const float*)d_in[6];
  const float* Wv = (const float*)d_in[7];
  const float* bv = (const float*)d_in[8];
  const float* Wo = (const float*)d_in[9];
  const float* bo = (const float*)d_in[10];
  float* out = (float*)d_out;

  char* ws = (char*)d_ws;
  const size_t MB = 1024 * 1024;
  unsigned short* xq16 = (unsigned short*)(ws + 0 * MB);
  unsigned short* xk16 = (unsigned short*)(ws + 8 * MB);
  unsigned short* xv16 = (unsigned short*)(ws + 16 * MB);
  unsigned short* wq16 = (unsigned short*)(ws + 24 * MB);
  unsigned short* wk16 = (unsigned short*)(ws + 26 * MB);
  unsigned short* wv16 = (unsigned short*)(ws + 28 * MB);
  unsigned short* qbuf  = (unsigned short*)(ws + 32 * MB);
  unsigned short* kbuf  = (unsigned short*)(ws + 40 * MB);
  unsigned short* vtbuf = (unsigned short*)(ws + 48 * MB);
  unsigned short* wo16  = (unsigned short*)(ws + 56 * MB);
  float* Lp  = (float*)(ws + 58 * MB);
  unsigned short* Op = (unsigned short*)(ws + 0 * MB);  // 2 x 8 MB bf16 partials (aliases dead x)
  unsigned short* obuf = qbuf;                          // aliases qbuf (dead after attn)

  ConvArgs ca;
  const int NX = ROWS * D_MODEL, NW = D_MODEL * D_MODEL;
  ca.s[0] = query; ca.d[0] = xq16; ca.n[0] = NX;
  ca.s[1] = key;   ca.d[1] = xk16; ca.n[1] = NX;
  ca.s[2] = value; ca.d[2] = xv16; ca.n[2] = NX;
  ca.s[3] = Wq;    ca.d[3] = wq16; ca.n[3] = NW;
  ca.s[4] = Wk;    ca.d[4] = wk16; ca.n[4] = NW;
  ca.s[5] = Wv;    ca.d[5] = wv16; ca.n[5] = NW;
  ca.s[6] = Wo;    ca.d[6] = wo16; ca.n[6] = NW;
  hipLaunchKernelGGL(convert_bf16, dim3(NX / 2048, 7), dim3(256), 0, stream, ca);

  dim3 gqkv(ROWS / 128, D_MODEL / 128, 3);  // 768 blocks
  hipLaunchKernelGGL(gemm_qkv, gqkv, dim3(256), 0, stream,
                     xq16, xk16, xv16, wq16, wk16, wv16, bq, bk, bv,
                     qbuf, kbuf, vtbuf);

  dim3 ga(S_LEN / 128, NH, BATCH * 2);      // 1024 blocks
  hipLaunchKernelGGL(attn_kernel, ga, dim3(256), 0, stream, qbuf, kbuf, vtbuf, Op, Lp);

  hipLaunchKernelGGL(merge_kernel, dim3(ROWS * D_MODEL / 2048), dim3(256), 0, stream,
                     Op, Lp, obuf);

  dim3 go(ROWS / 64, D_MODEL / 128);        // 512 blocks
  hipLaunchKernelGGL(gemm_o, go, dim3(256), 0, stream, obuf, wo16, bo, out);
}